// Round 1
// baseline (324.486 us; speedup 1.0000x reference)
//
#include <hip/hip_runtime.h>

#define B 8
#define XROWS 4096
#define AROWS 256
#define LC 4352        // AROWS + XROWS
#define DD 1024
#define KEEP 256
// n_dropped = LC - KEEP = 4096

__device__ __forceinline__ const float* combined_row(const float* __restrict__ x,
                                                     const float* __restrict__ act,
                                                     int b, int l) {
    return (l < AROWS) ? (act + ((size_t)b * AROWS + l) * DD)
                       : (x + ((size_t)b * XROWS + (l - AROWS)) * DD);
}

__global__ __launch_bounds__(256) void k_zero(float* __restrict__ p, int n) {
    int i = blockIdx.x * 256 + threadIdx.x;
    if (i < n) p[i] = 0.0f;
}

// Fused: salience[b,l] = combined[b,l,:].w_sal  AND  sums[b,d] = sum_l combined[b,l,d]
// grid = B * 68 blocks (64 rows each), block = 256 (4 waves, wave handles rows r=wave,wave+4,...)
__global__ __launch_bounds__(256) void k_sal_sums(
        const float* __restrict__ x, const float* __restrict__ act,
        const float* __restrict__ wsal, float* __restrict__ sal,
        float* __restrict__ sums) {
    const int tid  = threadIdx.x;
    const int wave = tid >> 6;
    const int lane = tid & 63;
    const int b     = blockIdx.x / 68;
    const int chunk = blockIdx.x % 68;
    const int row0  = chunk * 64;
    const int col   = lane * 16;   // lane owns 16 contiguous columns

    const float4 w0 = *(const float4*)(wsal + col + 0);
    const float4 w1 = *(const float4*)(wsal + col + 4);
    const float4 w2 = *(const float4*)(wsal + col + 8);
    const float4 w3 = *(const float4*)(wsal + col + 12);

    float4 c0 = make_float4(0,0,0,0), c1 = c0, c2 = c0, c3 = c0;

    for (int r = wave; r < 64; r += 4) {
        const int l = row0 + r;
        const float* rp = combined_row(x, act, b, l) + col;
        const float4 a0 = ((const float4*)rp)[0];
        const float4 a1 = ((const float4*)rp)[1];
        const float4 a2 = ((const float4*)rp)[2];
        const float4 a3 = ((const float4*)rp)[3];
        c0.x += a0.x; c0.y += a0.y; c0.z += a0.z; c0.w += a0.w;
        c1.x += a1.x; c1.y += a1.y; c1.z += a1.z; c1.w += a1.w;
        c2.x += a2.x; c2.y += a2.y; c2.z += a2.z; c2.w += a2.w;
        c3.x += a3.x; c3.y += a3.y; c3.z += a3.z; c3.w += a3.w;
        float s = a0.x*w0.x + a0.y*w0.y + a0.z*w0.z + a0.w*w0.w
                + a1.x*w1.x + a1.y*w1.y + a1.z*w1.z + a1.w*w1.w
                + a2.x*w2.x + a2.y*w2.y + a2.z*w2.z + a2.w*w2.w
                + a3.x*w3.x + a3.y*w3.y + a3.z*w3.z + a3.w*w3.w;
        #pragma unroll
        for (int m = 32; m >= 1; m >>= 1) s += __shfl_xor(s, m, 64);
        if (lane == 0) sal[b * LC + l] = s;
    }

    // combine per-wave column sums (wave-serial, no LDS atomics needed)
    __shared__ float acc[DD];
    for (int k = tid; k < DD; k += 256) acc[k] = 0.0f;
    __syncthreads();
    for (int w = 0; w < 4; ++w) {
        if (wave == w) {
            float* a = acc + col;
            a[0]+=c0.x;  a[1]+=c0.y;  a[2]+=c0.z;  a[3]+=c0.w;
            a[4]+=c1.x;  a[5]+=c1.y;  a[6]+=c1.z;  a[7]+=c1.w;
            a[8]+=c2.x;  a[9]+=c2.y;  a[10]+=c2.z; a[11]+=c2.w;
            a[12]+=c3.x; a[13]+=c3.y; a[14]+=c3.z; a[15]+=c3.w;
        }
        __syncthreads();
    }
    const int c4 = tid * 4;
    float* sb = sums + b * DD;
    atomicAdd(sb + c4 + 0, acc[c4 + 0]);
    atomicAdd(sb + c4 + 1, acc[c4 + 1]);
    atomicAdd(sb + c4 + 2, acc[c4 + 2]);
    atomicAdd(sb + c4 + 3, acc[c4 + 3]);
}

// Radix-select top-256 per batch; output indices ascending. grid = B, block = 1024.
__global__ __launch_bounds__(1024) void k_topk(const float* __restrict__ sal,
                                               int* __restrict__ idx) {
    const int b = blockIdx.x;
    const int tid = threadIdx.x;
    __shared__ unsigned keys[LC];
    __shared__ int scanbuf[1024];
    __shared__ int cntS;

    for (int i = tid; i < LC; i += 1024) {
        unsigned u = __float_as_uint(sal[b * LC + i]);
        keys[i] = (u & 0x80000000u) ? ~u : (u | 0x80000000u);  // monotone map
    }
    __syncthreads();

    // T = max value v with count(keys >= v) >= KEEP  (== KEEP-th largest key)
    unsigned T = 0;
    for (int bit = 31; bit >= 0; --bit) {
        const unsigned cand = T | (1u << bit);
        if (tid == 0) cntS = 0;
        __syncthreads();
        int c = 0;
        for (int i = tid; i < LC; i += 1024) c += (keys[i] >= cand) ? 1 : 0;
        #pragma unroll
        for (int m = 32; m >= 1; m >>= 1) c += __shfl_xor(c, m, 64);
        if ((tid & 63) == 0) atomicAdd(&cntS, c);
        __syncthreads();
        const int cnt = cntS;
        __syncthreads();
        if (cnt >= KEEP) T = cand;
    }

    // compact: all keys > T, plus earliest-index keys == T, ascending by index
    const int start = tid * 5;                // 1024*5 >= 4352, contiguous segments
    const int end = (start + 5 < LC) ? (start + 5) : LC;
    int gt = 0, eq = 0;
    for (int i = start; i < end; ++i) {
        if (i < LC) { gt += (keys[i] > T); eq += (keys[i] == T); }
    }
    scanbuf[tid] = (gt << 16) | eq;           // eq total <= 4352 < 65536, no carry
    for (int off = 1; off < 1024; off <<= 1) {
        __syncthreads();
        const int v = (tid >= off) ? scanbuf[tid - off] : 0;
        __syncthreads();
        scanbuf[tid] += v;
    }
    __syncthreads();
    const int total   = scanbuf[1023];
    const int incl    = scanbuf[tid];
    const int totalGT = total >> 16;
    const int needEQ  = KEEP - totalGT;       // >= 1, <= totalEQ
    int gtB = (incl >> 16) - gt;
    int eqB = (incl & 0xFFFF) - eq;
    for (int i = start; i < end; ++i) {
        if (i >= LC) break;
        const unsigned k = keys[i];
        if (k > T) {
            idx[b * KEEP + gtB + min(eqB, needEQ)] = i;
            ++gtB;
        } else if (k == T) {
            if (eqB < needEQ) idx[b * KEEP + gtB + eqB] = i;
            ++eqB;
        }
    }
}

// Gather kept rows -> new_active output; accumulate kept column sums.
// grid = B*8 (32 rows/block), block = 256 (thread owns 4 columns)
__global__ __launch_bounds__(256) void k_gather(const float* __restrict__ x,
        const float* __restrict__ act, const int* __restrict__ idx,
        float* __restrict__ out_active, float* __restrict__ ksum) {
    const int b = blockIdx.x >> 3;
    const int chunk = blockIdx.x & 7;
    const int tid = threadIdx.x;
    const int c4 = tid * 4;
    float4 cs = make_float4(0,0,0,0);
    for (int r = 0; r < 32; ++r) {
        const int k = chunk * 32 + r;
        const int l = idx[b * KEEP + k];
        const float4 v = *(const float4*)(combined_row(x, act, b, l) + c4);
        *(float4*)(out_active + ((size_t)b * KEEP + k) * DD + c4) = v;
        cs.x += v.x; cs.y += v.y; cs.z += v.z; cs.w += v.w;
    }
    float* kb = ksum + b * DD;
    atomicAdd(kb + c4 + 0, cs.x);
    atomicAdd(kb + c4 + 1, cs.y);
    atomicAdd(kb + c4 + 2, cs.z);
    atomicAdd(kb + c4 + 3, cs.w);
}

// cold_new + ctx. grid = 32, block = 256 (B*DD = 8192 threads)
__global__ __launch_bounds__(256) void k_ctx(const float* __restrict__ sums,
        const float* __restrict__ ksum, const float* __restrict__ cold,
        float* __restrict__ out_cold, float* __restrict__ ctx) {
    const int i = blockIdx.x * 256 + threadIdx.x;
    const float s = sums[i];
    const float ks = ksum[i];
    const float dm = (s - ks) * (1.0f / 4096.0f);     // dropped mean
    const float cn = 0.9f * cold[i] + 0.1f * dm;
    out_cold[i] = cn;
    ctx[i] = ks * (1.0f / 256.0f) + cn;               // active_ctx + cold_new
}

// rvec[b,e] = sum_d ctx[b,d] * w_read[e,d]. grid = 1024 (one e per block), block = 256
__global__ __launch_bounds__(256) void k_read(const float* __restrict__ ctx,
        const float* __restrict__ wread, float* __restrict__ rvec) {
    const int e = blockIdx.x;
    const int tid = threadIdx.x;
    const int c4 = tid * 4;
    const float4 w = *(const float4*)(wread + (size_t)e * DD + c4);
    float p[B];
    #pragma unroll
    for (int bb = 0; bb < B; ++bb) {
        const float4 c = *(const float4*)(ctx + bb * DD + c4);
        p[bb] = w.x*c.x + w.y*c.y + w.z*c.z + w.w*c.w;
    }
    __shared__ float red[B][256];
    #pragma unroll
    for (int bb = 0; bb < B; ++bb) red[bb][tid] = p[bb];
    __syncthreads();
    for (int s = 128; s > 0; s >>= 1) {
        if (tid < s) {
            #pragma unroll
            for (int bb = 0; bb < B; ++bb) red[bb][tid] += red[bb][tid + s];
        }
        __syncthreads();
    }
    if (tid < B) rvec[tid * DD + e] = red[tid][0];
}

// x_out = x + rvec broadcast. grid-stride over float4s.
__global__ __launch_bounds__(256) void k_xout(const float* __restrict__ x,
        const float* __restrict__ rvec, float* __restrict__ xout) {
    const size_t total = (size_t)B * XROWS * (DD / 4);   // 8,388,608 float4s
    const float4* x4 = (const float4*)x;
    const float4* r4 = (const float4*)rvec;
    float4* o4 = (float4*)xout;
    for (size_t i = (size_t)blockIdx.x * 256 + threadIdx.x; i < total;
         i += (size_t)gridDim.x * 256) {
        float4 v = x4[i];
        const int e4 = (int)(i & 255);          // DD/4 = 256
        const int bb = (int)(i >> 20);          // XROWS*DD/4 = 2^20 per batch
        const float4 r = r4[(bb << 8) | e4];
        v.x += r.x; v.y += r.y; v.z += r.z; v.w += r.w;
        o4[i] = v;
    }
}

extern "C" void kernel_launch(void* const* d_in, const int* in_sizes, int n_in,
                              void* d_out, int out_size, void* d_ws, size_t ws_size,
                              hipStream_t stream) {
    (void)in_sizes; (void)n_in; (void)out_size; (void)ws_size;
    const float* x     = (const float*)d_in[0];   // [B, XROWS, DD]
    const float* act   = (const float*)d_in[1];   // [B, AROWS, DD]
    const float* cold  = (const float*)d_in[2];   // [B, DD]
    const float* wsal  = (const float*)d_in[3];   // [DD]
    const float* wread = (const float*)d_in[4];   // [DD, DD]

    float* out        = (float*)d_out;
    float* xout       = out;                                   // B*XROWS*DD
    float* out_active = xout + (size_t)B * XROWS * DD;         // B*KEEP*DD
    float* out_cold   = out_active + (size_t)B * KEEP * DD;    // B*DD

    float* ws   = (float*)d_ws;
    float* sal  = ws;                   // B*LC   = 34816
    float* sums = sal + B * LC;         // B*DD   = 8192
    float* ksum = sums + B * DD;        // 8192
    float* ctx  = ksum + B * DD;        // 8192
    float* rvec = ctx + B * DD;         // 8192
    int*   idx  = (int*)(rvec + B * DD);// B*KEEP = 2048 ints

    // zero the two atomic accumulators (sums, ksum are adjacent)
    k_zero<<<(2 * B * DD + 255) / 256, 256, 0, stream>>>(sums, 2 * B * DD);
    k_sal_sums<<<B * 68, 256, 0, stream>>>(x, act, wsal, sal, sums);
    k_topk<<<B, 1024, 0, stream>>>(sal, idx);
    k_gather<<<B * 8, 256, 0, stream>>>(x, act, idx, out_active, ksum);
    k_ctx<<<(B * DD) / 256, 256, 0, stream>>>(sums, ksum, cold, out_cold, ctx);
    k_read<<<DD, 256, 0, stream>>>(ctx, wread, rvec);
    k_xout<<<8192, 256, 0, stream>>>(x, rvec, xout);
}

// Round 3
// 306.220 us; speedup vs baseline: 1.0597x; 1.0597x over previous
//
#include <hip/hip_runtime.h>

#define B 8
#define XROWS 4096
#define AROWS 256
#define LC 4352        // AROWS + XROWS
#define DD 1024
#define KEEP 256
// n_dropped = LC - KEEP = 4096

typedef float vfloat4 __attribute__((ext_vector_type(4)));

__device__ __forceinline__ void nt_store4(const float4& v, float* p) {
    vfloat4 t = {v.x, v.y, v.z, v.w};
    __builtin_nontemporal_store(t, (vfloat4*)p);
}

__device__ __forceinline__ const float* combined_row(const float* __restrict__ x,
                                                     const float* __restrict__ act,
                                                     int b, int l) {
    return (l < AROWS) ? (act + ((size_t)b * AROWS + l) * DD)
                       : (x + ((size_t)b * XROWS + (l - AROWS)) * DD);
}

__global__ __launch_bounds__(256) void k_zero(float* __restrict__ p, int n) {
    int i = blockIdx.x * 256 + threadIdx.x;
    if (i < n) p[i] = 0.0f;
}

// Fused: salience[b,l] = combined[b,l,:].w_sal  AND  sums[b,d] += sum_l combined[b,l,d]
// grid = B * 136 blocks (32 rows each), block = 256 (4 waves; wave handles rows r=wave,wave+4,...)
// Unit-stride loads: lane i reads chunk j at row + j*256 + i*4 floats (wave = 1KB contiguous).
__global__ __launch_bounds__(256) void k_sal_sums(
        const float* __restrict__ x, const float* __restrict__ act,
        const float* __restrict__ wsal, float* __restrict__ sal,
        float* __restrict__ sums) {
    const int tid  = threadIdx.x;
    const int wave = tid >> 6;
    const int lane = tid & 63;
    const int b     = blockIdx.x / 136;
    const int chunk = blockIdx.x % 136;
    const int row0  = chunk * 32;
    const int c0 = lane * 4;       // lane's float4 within each 256-col chunk

    const float4 w0 = *(const float4*)(wsal + 0 * 256 + c0);
    const float4 w1 = *(const float4*)(wsal + 1 * 256 + c0);
    const float4 w2 = *(const float4*)(wsal + 2 * 256 + c0);
    const float4 w3 = *(const float4*)(wsal + 3 * 256 + c0);

    float4 s0 = make_float4(0,0,0,0), s1 = s0, s2 = s0, s3 = s0;

    for (int r = wave; r < 32; r += 4) {
        const int l = row0 + r;
        const float* rp = combined_row(x, act, b, l);
        const float4 a0 = *(const float4*)(rp + 0 * 256 + c0);
        const float4 a1 = *(const float4*)(rp + 1 * 256 + c0);
        const float4 a2 = *(const float4*)(rp + 2 * 256 + c0);
        const float4 a3 = *(const float4*)(rp + 3 * 256 + c0);
        s0.x += a0.x; s0.y += a0.y; s0.z += a0.z; s0.w += a0.w;
        s1.x += a1.x; s1.y += a1.y; s1.z += a1.z; s1.w += a1.w;
        s2.x += a2.x; s2.y += a2.y; s2.z += a2.z; s2.w += a2.w;
        s3.x += a3.x; s3.y += a3.y; s3.z += a3.z; s3.w += a3.w;
        float s = a0.x*w0.x + a0.y*w0.y + a0.z*w0.z + a0.w*w0.w
                + a1.x*w1.x + a1.y*w1.y + a1.z*w1.z + a1.w*w1.w
                + a2.x*w2.x + a2.y*w2.y + a2.z*w2.z + a2.w*w2.w
                + a3.x*w3.x + a3.y*w3.y + a3.z*w3.z + a3.w*w3.w;
        #pragma unroll
        for (int m = 32; m >= 1; m >>= 1) s += __shfl_xor(s, m, 64);
        if (lane == 0) sal[b * LC + l] = s;
    }

    // parallel combine: each wave owns acc[wave][*], single barrier
    __shared__ float acc[4][DD];
    float* aw = acc[wave];
    *(float4*)(aw + 0 * 256 + c0) = s0;
    *(float4*)(aw + 1 * 256 + c0) = s1;
    *(float4*)(aw + 2 * 256 + c0) = s2;
    *(float4*)(aw + 3 * 256 + c0) = s3;
    __syncthreads();
    const int col = tid * 4;
    float4 t0 = *(const float4*)(acc[0] + col);
    float4 t1 = *(const float4*)(acc[1] + col);
    float4 t2 = *(const float4*)(acc[2] + col);
    float4 t3 = *(const float4*)(acc[3] + col);
    float* sb = sums + b * DD;
    atomicAdd(sb + col + 0, t0.x + t1.x + t2.x + t3.x);
    atomicAdd(sb + col + 1, t0.y + t1.y + t2.y + t3.y);
    atomicAdd(sb + col + 2, t0.z + t1.z + t2.z + t3.z);
    atomicAdd(sb + col + 3, t0.w + t1.w + t2.w + t3.w);
}

// 8-bit histogram radix select of the KEEP-th largest key per batch + ascending
// tie-safe index compaction. grid = B, block = 1024. Also zeros ksum[b].
__global__ __launch_bounds__(1024) void k_topk(const float* __restrict__ sal,
                                               int* __restrict__ idx,
                                               float* __restrict__ ksum) {
    const int b = blockIdx.x;
    const int tid = threadIdx.x;
    const int lane = tid & 63;
    __shared__ unsigned keys[LC];
    __shared__ int hist[256];
    __shared__ int wtot4[4];
    __shared__ int wtot16[16];
    __shared__ unsigned prefS;
    __shared__ int kremS;

    if (tid < DD) ksum[b * DD + tid] = 0.0f;   // zero for k_gather's atomics

    for (int i = tid; i < LC; i += 1024) {
        unsigned u = __float_as_uint(sal[b * LC + i]);
        keys[i] = (u & 0x80000000u) ? ~u : (u | 0x80000000u);  // monotone map
    }
    if (tid == 0) { prefS = 0u; kremS = KEEP; }
    __syncthreads();

    for (int pass = 0; pass < 4; ++pass) {
        const int shift = 24 - 8 * pass;
        if (tid < 256) hist[tid] = 0;
        __syncthreads();
        const unsigned pref = prefS;
        const int krem = kremS;
        for (int i = tid; i < LC; i += 1024) {
            const unsigned k = keys[i];
            if (pass == 0 || (k >> (shift + 8)) == (pref >> (shift + 8)))
                atomicAdd(&hist[(k >> shift) & 255], 1);
        }
        __syncthreads();
        int h = 0, cum = 0;
        if (tid < 256) {
            h = hist[tid];
            cum = h;
            // suffix-inclusive within wave (bins tid..wave_end): cum(t) = #keys with byte >= t (wave-local)
            #pragma unroll
            for (int off = 1; off <= 32; off <<= 1) {
                int v = __shfl_down(cum, off, 64);
                if (lane + off < 64) cum += v;
            }
            if (lane == 0) wtot4[tid >> 6] = cum;
        }
        __syncthreads();
        if (tid < 256) {
            for (int w2 = (tid >> 6) + 1; w2 < 4; ++w2) cum += wtot4[w2];
            // selected bin: cum >= krem and count(byte > tid) = cum - h < krem
            if (cum >= krem && (cum - h) < krem) {
                prefS = pref | ((unsigned)tid << shift);
                kremS = krem - (cum - h);
            }
        }
        __syncthreads();
    }

    const unsigned T = prefS;
    const int needEQ = kremS;   // = KEEP - count(keys > T), >= 1

    // contiguous 5-wide segments per thread; block scan via wave shfl + 16 wave totals
    const int start = tid * 5;
    const int end = (start + 5 < LC) ? (start + 5) : LC;
    int gt = 0, eq = 0;
    for (int i = start; i < end; ++i) {
        const unsigned k = keys[i];
        gt += (k > T);
        eq += (k == T);
    }
    int packed = (gt << 16) | eq;
    int p = packed;
    #pragma unroll
    for (int off = 1; off <= 32; off <<= 1) {
        int v = __shfl_up(p, off, 64);
        if (lane >= off) p += v;
    }
    if (lane == 63) wtot16[tid >> 6] = p;
    __syncthreads();
    int base = 0;
    for (int w2 = 0; w2 < (tid >> 6); ++w2) base += wtot16[w2];
    const int exc = p - packed + base;
    int gtB = exc >> 16;
    int eqB = exc & 0xFFFF;
    for (int i = start; i < end; ++i) {
        const unsigned k = keys[i];
        if (k > T) {
            idx[b * KEEP + gtB + min(eqB, needEQ)] = i;
            ++gtB;
        } else if (k == T) {
            if (eqB < needEQ) idx[b * KEEP + gtB + eqB] = i;
            ++eqB;
        }
    }
}

// Gather kept rows -> new_active output (NT stores); accumulate kept column sums.
// grid = B*8 (32 rows/block), block = 256 (thread owns 4 columns)
__global__ __launch_bounds__(256) void k_gather(const float* __restrict__ x,
        const float* __restrict__ act, const int* __restrict__ idx,
        float* __restrict__ out_active, float* __restrict__ ksum) {
    const int b = blockIdx.x >> 3;
    const int chunk = blockIdx.x & 7;
    const int tid = threadIdx.x;
    const int c4 = tid * 4;
    float4 cs = make_float4(0,0,0,0);
    for (int r = 0; r < 32; ++r) {
        const int k = chunk * 32 + r;
        const int l = idx[b * KEEP + k];
        const float4 v = *(const float4*)(combined_row(x, act, b, l) + c4);
        nt_store4(v, out_active + ((size_t)b * KEEP + k) * DD + c4);
        cs.x += v.x; cs.y += v.y; cs.z += v.z; cs.w += v.w;
    }
    float* kb = ksum + b * DD;
    atomicAdd(kb + c4 + 0, cs.x);
    atomicAdd(kb + c4 + 1, cs.y);
    atomicAdd(kb + c4 + 2, cs.z);
    atomicAdd(kb + c4 + 3, cs.w);
}

// Fused ctx + read projection: each block computes full ctx in LDS from
// sums/ksum/cold, block 0 also writes out_cold; then rvec[b,e] = ctx[b,:].w_read[e,:].
// grid = DD (one e per block), block = 256.
__global__ __launch_bounds__(256) void k_read(const float* __restrict__ sums,
        const float* __restrict__ ksum, const float* __restrict__ cold,
        const float* __restrict__ wread, float* __restrict__ rvec,
        float* __restrict__ out_cold) {
    const int e = blockIdx.x;
    const int tid = threadIdx.x;
    const int wave = tid >> 6;
    const int lane = tid & 63;
    const int c4 = tid * 4;
    __shared__ float ctxs[B][DD];
    __shared__ float part[4][B];

    #pragma unroll
    for (int bb = 0; bb < B; ++bb) {
        const float4 s  = *(const float4*)(sums + bb * DD + c4);
        const float4 ks = *(const float4*)(ksum + bb * DD + c4);
        const float4 cd = *(const float4*)(cold + bb * DD + c4);
        float4 cn, cx;
        cn.x = 0.9f * cd.x + 0.1f * ((s.x - ks.x) * (1.0f / 4096.0f));
        cn.y = 0.9f * cd.y + 0.1f * ((s.y - ks.y) * (1.0f / 4096.0f));
        cn.z = 0.9f * cd.z + 0.1f * ((s.z - ks.z) * (1.0f / 4096.0f));
        cn.w = 0.9f * cd.w + 0.1f * ((s.w - ks.w) * (1.0f / 4096.0f));
        cx.x = ks.x * (1.0f / 256.0f) + cn.x;
        cx.y = ks.y * (1.0f / 256.0f) + cn.y;
        cx.z = ks.z * (1.0f / 256.0f) + cn.z;
        cx.w = ks.w * (1.0f / 256.0f) + cn.w;
        *(float4*)(&ctxs[bb][c4]) = cx;
        if (e == 0) *(float4*)(out_cold + bb * DD + c4) = cn;
    }
    __syncthreads();

    const float4 w = *(const float4*)(wread + (size_t)e * DD + c4);
    float p[B];
    #pragma unroll
    for (int bb = 0; bb < B; ++bb) {
        const float4 c = *(const float4*)(&ctxs[bb][c4]);
        p[bb] = w.x*c.x + w.y*c.y + w.z*c.z + w.w*c.w;
    }
    #pragma unroll
    for (int bb = 0; bb < B; ++bb) {
        #pragma unroll
        for (int m = 32; m >= 1; m >>= 1) p[bb] += __shfl_xor(p[bb], m, 64);
        if (lane == 0) part[wave][bb] = p[bb];
    }
    __syncthreads();
    if (tid < B) rvec[tid * DD + e] = part[0][tid] + part[1][tid] + part[2][tid] + part[3][tid];
}

// x_out = x + rvec broadcast. grid-stride over float4s, NT stores.
__global__ __launch_bounds__(256) void k_xout(const float* __restrict__ x,
        const float* __restrict__ rvec, float* __restrict__ xout) {
    const size_t total = (size_t)B * XROWS * (DD / 4);   // 8,388,608 float4s
    const float4* x4 = (const float4*)x;
    const float4* r4 = (const float4*)rvec;
    float* of = (float*)xout;
    for (size_t i = (size_t)blockIdx.x * 256 + threadIdx.x; i < total;
         i += (size_t)gridDim.x * 256) {
        float4 v = x4[i];
        const int e4 = (int)(i & 255);          // DD/4 = 256
        const int bb = (int)(i >> 20);          // XROWS*DD/4 = 2^20 per batch
        const float4 r = r4[(bb << 8) | e4];
        v.x += r.x; v.y += r.y; v.z += r.z; v.w += r.w;
        nt_store4(v, of + i * 4);
    }
}

extern "C" void kernel_launch(void* const* d_in, const int* in_sizes, int n_in,
                              void* d_out, int out_size, void* d_ws, size_t ws_size,
                              hipStream_t stream) {
    (void)in_sizes; (void)n_in; (void)out_size; (void)ws_size;
    const float* x     = (const float*)d_in[0];   // [B, XROWS, DD]
    const float* act   = (const float*)d_in[1];   // [B, AROWS, DD]
    const float* cold  = (const float*)d_in[2];   // [B, DD]
    const float* wsal  = (const float*)d_in[3];   // [DD]
    const float* wread = (const float*)d_in[4];   // [DD, DD]

    float* out        = (float*)d_out;
    float* xout       = out;                                   // B*XROWS*DD
    float* out_active = xout + (size_t)B * XROWS * DD;         // B*KEEP*DD
    float* out_cold   = out_active + (size_t)B * KEEP * DD;    // B*DD

    float* ws   = (float*)d_ws;
    float* sal  = ws;                   // B*LC   = 34816
    float* sums = sal + B * LC;         // B*DD   = 8192
    float* ksum = sums + B * DD;        // 8192
    float* rvec = ksum + B * DD;        // 8192
    int*   idx  = (int*)(rvec + B * DD);// B*KEEP = 2048 ints

    k_zero<<<(B * DD + 255) / 256, 256, 0, stream>>>(sums, B * DD);
    k_sal_sums<<<B * 136, 256, 0, stream>>>(x, act, wsal, sal, sums);
    k_topk<<<B, 1024, 0, stream>>>(sal, idx, ksum);
    k_gather<<<B * 8, 256, 0, stream>>>(x, act, idx, out_active, ksum);
    k_read<<<DD, 256, 0, stream>>>(sums, ksum, cold, wread, rvec, out_cold);
    k_xout<<<8192, 256, 0, stream>>>(x, rvec, xout);
}